// Round 8
// baseline (478.603 us; speedup 1.0000x reference)
//
#include <hip/hip_runtime.h>
#include <hip/hip_bf16.h>
#include <stdint.h>

typedef unsigned short u16;
typedef short bf16x8 __attribute__((ext_vector_type(8)));
typedef float f32x4 __attribute__((ext_vector_type(4)));

__device__ __forceinline__ float us2f(u16 u) {
    union { unsigned int i; float f; } x;
    x.i = ((unsigned int)u) << 16;
    return x.f;
}

__device__ __forceinline__ u16 f2us(float f) {
    union { float f; unsigned int i; } x; x.f = f;
    unsigned int lsb = (x.i >> 16) & 1u;
    x.i += 0x7FFFu + lsb;            // round-to-nearest-even
    return (u16)(x.i >> 16);
}

// async global->LDS, 16B per lane. LDS dest = wave-uniform base + lane*16.
__device__ __forceinline__ void gl_lds16(const u16* g, u16* l) {
    __builtin_amdgcn_global_load_lds(
        (const __attribute__((address_space(1))) void*)(uintptr_t)(const void*)g,
        (__attribute__((address_space(3))) void*)(uintptr_t)(void*)l,
        16, 0, 0);
}

#define FLAG_ROPE2  1   // region2 cols get interleaved RoPE via table (hd 512)
#define FLAG_TRANS2 4   // region2 written transposed (LDC2 = rows stride)
#define FLAG_F32OUT 8   // region1 written fp32

struct GArgs {
    const u16 *A0, *B0, *B0r2;
    int K0;
    const float* bias;          // indexed by global col (concatenated)
    const float2* ropeTab;      // [512][256] (cos,sin), pos-major
    void* C; void* C2;
    int colSplit;               // cols >= colSplit -> region2 (multiple of 128)
};

// ---------------------------------------------------------------------------
// NT MFMA GEMM: C[m,n] = sum_k A[m,k]*Bt[n,k]. 128x128 tile, BK=64,
// 256 threads = 4 waves 2x2, each wave 64x64 (4x4 MFMA subtiles).
// bf16 in (K-major both sides), fp32 accum. Column-split epilogue: cols >=
// colSplit go to C2 (optionally RoPE'd or transposed), B rows from B0r2.
// LDS rotation: slot s of row r holds chunk (s - r) & 7 (measured 0 confl).
// RoPE epilogue is TABLE-BASED (r8): 1 float2 load + 1 shfl + 2 fma per
// element, replacing 12 sincos + ~128 chained fma per thread (r5-r7 showed
// VALUBusy 43-45% on the rope-heavy up-proj q dispatch).
// ---------------------------------------------------------------------------
template <int LDA0, int LDB0, int LDC, int LDC2, int FLAGS>
__global__ __launch_bounds__(256)
void gemm_mfma(GArgs g)
{
    __shared__ u16 As[128 * 64];   // 16 KB
    __shared__ u16 Bs[128 * 64];   // 16 KB

    const int t    = threadIdx.x;
    const int lane = t & 63;
    const int w    = t >> 6;
    const int wm   = w >> 1, wn = w & 1;
    const int m0   = blockIdx.y * 128;
    const int n0   = blockIdx.x * 128;
    const bool r2  = (n0 >= g.colSplit);

    const int srow = t >> 3;    // 0..31 base row for staging
    const int sp   = t & 7;     // LDS slot within row
    u16* dA = As + t * 8;
    u16* dB = Bs + t * 8;

    const int lr = lane & 15;
    const int jj = lane >> 4;

    f32x4 acc[4][4];
#pragma unroll
    for (int i = 0; i < 4; ++i)
#pragma unroll
        for (int j = 0; j < 4; ++j)
            acc[i][j] = (f32x4){0.f, 0.f, 0.f, 0.f};

    {
        const u16* A = g.A0;
        const u16* B = r2 ? g.B0r2 - (long)g.colSplit * LDB0 : g.B0;
        const u16* gA[4];
        const u16* gB[4];
#pragma unroll
        for (int r = 0; r < 4; ++r) {
            int row = r * 32 + srow;
            int gc  = (sp - row) & 7;
            gA[r] = A + (long)(m0 + row) * LDA0 + gc * 8;
            gB[r] = B + (long)(n0 + row) * LDB0 + gc * 8;
        }
        for (int kt = 0; kt < g.K0; kt += 64) {
#pragma unroll
            for (int r = 0; r < 4; ++r) {
                gl_lds16(gA[r], dA + r * 2048);
                gl_lds16(gB[r], dB + r * 2048);
                gA[r] += 64; gB[r] += 64;
            }
            __syncthreads();
#pragma unroll
            for (int s = 0; s < 2; ++s) {
                bf16x8 af[4], bfr[4];
#pragma unroll
                for (int mi = 0; mi < 4; ++mi) {
                    int row  = wm * 64 + mi * 16 + lr;
                    int slot = (s * 4 + jj + row) & 7;
                    af[mi] = *(const bf16x8*)&As[row * 64 + slot * 8];
                }
#pragma unroll
                for (int ni = 0; ni < 4; ++ni) {
                    int row  = wn * 64 + ni * 16 + lr;
                    int slot = (s * 4 + jj + row) & 7;
                    bfr[ni] = *(const bf16x8*)&Bs[row * 64 + slot * 8];
                }
#pragma unroll
                for (int mi = 0; mi < 4; ++mi)
#pragma unroll
                    for (int ni = 0; ni < 4; ++ni)
                        acc[mi][ni] = __builtin_amdgcn_mfma_f32_16x16x32_bf16(
                            af[mi], bfr[ni], acc[mi][ni], 0, 0, 0);
            }
            __syncthreads();
        }
    }

    // epilogue. C/D layout: col = lane&15, row = (lane>>4)*4 + reg.
    const int eCol0 = n0 + wn * 64 + lr;
    const int eRow0 = m0 + wm * 64 + jj * 4;
    const bool oddc = lane & 1;

    if (g.bias) {
#pragma unroll
        for (int ni = 0; ni < 4; ++ni) {
            float bv = g.bias[eCol0 + ni * 16];
#pragma unroll
            for (int mi = 0; mi < 4; ++mi) {
                acc[mi][ni][0] += bv; acc[mi][ni][1] += bv;
                acc[mi][ni][2] += bv; acc[mi][ni][3] += bv;
            }
        }
    }

    if (!r2) {
#pragma unroll
        for (int mi = 0; mi < 4; ++mi)
#pragma unroll
            for (int ni = 0; ni < 4; ++ni) {
                int rowb = eRow0 + mi * 16;
                int colg = eCol0 + ni * 16;
                if (FLAGS & FLAG_F32OUT) {
                    float* cp = (float*)g.C;
#pragma unroll
                    for (int i = 0; i < 4; ++i)
                        cp[(long)(rowb + i) * LDC + colg] = acc[mi][ni][i];
                } else {
                    u16* cp = (u16*)g.C;
#pragma unroll
                    for (int i = 0; i < 4; ++i)
                        cp[(long)(rowb + i) * LDC + colg] = f2us(acc[mi][ni][i]);
                }
            }
    } else if (FLAGS & FLAG_ROPE2) {
        // table RoPE: rows never wrap mod 512 within a block (m0%512 fixed),
        // cols of one ni share a pair index. even lane: o=v*c-other*s;
        // odd lane: o=v*c+other*s  (interleaved rotation, matches reference).
        const float2* rt = g.ropeTab;
#pragma unroll
        for (int ni = 0; ni < 4; ++ni) {
            int col2 = eCol0 + ni * 16 - g.colSplit;
            int pair = (col2 & 511) >> 1;
#pragma unroll
            for (int mi = 0; mi < 4; ++mi) {
                f32x4 v = acc[mi][ni];
                int rowb = eRow0 + mi * 16;
                u16* cp = (u16*)g.C2;
#pragma unroll
                for (int i = 0; i < 4; ++i) {
                    float2 cs = rt[((rowb + i) & 511) * 256 + pair];
                    float other = __shfl_xor(v[i], 1, 64);
                    float ov = oddc ? (v[i] * cs.x + other * cs.y)
                                    : (v[i] * cs.x - other * cs.y);
                    cp[(long)(rowb + i) * LDC2 + col2] = f2us(ov);
                }
            }
        }
    } else {
#pragma unroll
        for (int mi = 0; mi < 4; ++mi)
#pragma unroll
            for (int ni = 0; ni < 4; ++ni) {
                int rowb = eRow0 + mi * 16;
                int col2 = eCol0 + ni * 16 - g.colSplit;
                if (FLAGS & FLAG_TRANS2) {
                    u16* cp = (u16*)g.C2 + (long)col2 * LDC2 + rowb;
                    ushort4 o4;
                    o4.x = f2us(acc[mi][ni][0]); o4.y = f2us(acc[mi][ni][1]);
                    o4.z = f2us(acc[mi][ni][2]); o4.w = f2us(acc[mi][ni][3]);
                    *(ushort4*)cp = o4;
                } else {
                    u16* cp = (u16*)g.C2;
#pragma unroll
                    for (int i = 0; i < 4; ++i)
                        cp[(long)(rowb + i) * LDC2 + col2] = f2us(acc[mi][ni][i]);
                }
            }
    }
}

// ---------------------------------------------------------------------------
// Fused attention (round-5 verbatim: best measured 82.5 us, 524K confl).
// per block = (b, h, 128 q-rows). Loops 4 key-tiles of 128:
//   S = qc.kc^T (K=128) + qr.kr^T (K=512)   [BK=64 staged, MFMA]
//   P = exp(S*scale) -> Ps (stride 136); l_sum partials (LDS atomics)
//   O += P.V  (V staged into Bs, 2 halves)
// XCD swizzle: 4 q-tile sharers of one z on the same XCD; bb = xcd
// (r5-measured FETCH 246->183 MB).
// ---------------------------------------------------------------------------
__global__ __launch_bounds__(256, 2)
void attn_fused(const u16* __restrict__ qc, const u16* __restrict__ kc,
                const u16* __restrict__ qr, const u16* __restrict__ kr,
                const u16* __restrict__ vt, u16* __restrict__ o)
{
    __shared__ u16 As[128 * 64];       // 16 KB  (BK=64)
    __shared__ u16 Bs[128 * 64];       // 16 KB
    __shared__ u16 Ps[128 * 136];      // 34 KB (pad 128->136 for banks)
    __shared__ float l_sum[128];

    const int t    = threadIdx.x;
    const int lane = t & 63;
    const int w    = t >> 6;
    const int wm   = w >> 1, wn = w & 1;

    const int flat = blockIdx.x + (blockIdx.y << 2);   // hw dispatch order
    const int xcd  = flat & 7;
    const int j    = flat >> 3;                        // 0..63
    const int m0   = (j >> 4) * 128;
    const int z    = xcd * 16 + (j & 15);              // 0..127
    const int bb   = z >> 4, h = z & 15;

    if (t < 128) l_sum[t] = 0.f;

    const int srow = t >> 3;
    const int sp   = t & 7;
    u16* dA = As + t * 8;
    u16* dB = Bs + t * 8;
    int rrow[4], rgc[4];
#pragma unroll
    for (int r = 0; r < 4; ++r) {
        rrow[r] = r * 32 + srow;
        rgc[r]  = (sp - rrow[r]) & 7;
    }

    const int lr = lane & 15;
    const int jj = lane >> 4;

    const u16* gqc[4];
    const u16* gqr[4];
#pragma unroll
    for (int r = 0; r < 4; ++r) {
        gqc[r] = qc + (long)(bb * 512 + m0 + rrow[r]) * 2048 + h * 128 + rgc[r] * 8;
        gqr[r] = qr + (long)(bb * 512 + m0 + rrow[r]) * 8192 + h * 512 + rgc[r] * 8;
    }

    f32x4 acc_o[4][4];
#pragma unroll
    for (int i = 0; i < 4; ++i)
#pragma unroll
        for (int j2 = 0; j2 < 4; ++j2) acc_o[i][j2] = (f32x4){0.f, 0.f, 0.f, 0.f};

    const float scale = 1.0f / 33.941125496954285f;   // 1/(sqrt(128)+sqrt(512))

    for (int nt = 0; nt < 4; ++nt) {
        const int n0k = nt * 128;

        f32x4 acc_s[4][4];
#pragma unroll
        for (int i = 0; i < 4; ++i)
#pragma unroll
            for (int j2 = 0; j2 < 4; ++j2) acc_s[i][j2] = (f32x4){0.f, 0.f, 0.f, 0.f};

        const u16* pa[4];
        const u16* pb[4];
#pragma unroll
        for (int r = 0; r < 4; ++r) {
            pa[r] = gqc[r];
            pb[r] = kc + (long)(bb * 512 + n0k + rrow[r]) * 2048 + h * 128 + rgc[r] * 8;
        }
        for (int seg = 0; seg < 2; ++seg) {
            int iters = seg == 0 ? 2 : 8;        // K=128, then K=512
            for (int kt = 0; kt < iters; ++kt) {
#pragma unroll
                for (int r = 0; r < 4; ++r) {
                    gl_lds16(pa[r], dA + r * 2048);
                    gl_lds16(pb[r], dB + r * 2048);
                    pa[r] += 64; pb[r] += 64;
                }
                __syncthreads();
#pragma unroll
                for (int s = 0; s < 2; ++s) {
                    bf16x8 af[4], bfr[4];
#pragma unroll
                    for (int mi = 0; mi < 4; ++mi) {
                        int row  = wm * 64 + mi * 16 + lr;
                        int slot = (s * 4 + jj + row) & 7;
                        af[mi] = *(const bf16x8*)&As[row * 64 + slot * 8];
                    }
#pragma unroll
                    for (int ni = 0; ni < 4; ++ni) {
                        int row  = wn * 64 + ni * 16 + lr;
                        int slot = (s * 4 + jj + row) & 7;
                        bfr[ni] = *(const bf16x8*)&Bs[row * 64 + slot * 8];
                    }
#pragma unroll
                    for (int mi = 0; mi < 4; ++mi)
#pragma unroll
                        for (int ni = 0; ni < 4; ++ni)
                            acc_s[mi][ni] = __builtin_amdgcn_mfma_f32_16x16x32_bf16(
                                af[mi], bfr[ni], acc_s[mi][ni], 0, 0, 0);
                }
                __syncthreads();
            }
            if (seg == 0) {
#pragma unroll
                for (int r = 0; r < 4; ++r) {
                    pa[r] = gqr[r];
                    pb[r] = kr + (long)(bb * 512 + n0k + rrow[r]) * 1536 + rgc[r] * 8;
                }
            }
        }

        // ---- P = exp(S*scale) -> Ps; l partial sums -> l_sum ----
#pragma unroll
        for (int mi = 0; mi < 4; ++mi) {
            float rowpart[4] = {0.f, 0.f, 0.f, 0.f};
#pragma unroll
            for (int ni = 0; ni < 4; ++ni) {
                f32x4 v = acc_s[mi][ni];
                int colP = wn * 64 + ni * 16 + lr;
#pragma unroll
                for (int i = 0; i < 4; ++i) {
                    float e = __expf(v[i] * scale);
                    rowpart[i] += e;
                    int rowP = wm * 64 + mi * 16 + jj * 4 + i;
                    Ps[rowP * 136 + colP] = f2us(e);
                }
            }
#pragma unroll
            for (int i = 0; i < 4; ++i) {
                float s4 = rowpart[i];
                s4 += __shfl_xor(s4, 1, 64);
                s4 += __shfl_xor(s4, 2, 64);
                s4 += __shfl_xor(s4, 4, 64);
                s4 += __shfl_xor(s4, 8, 64);
                if ((lane & 15) == 0)
                    atomicAdd(&l_sum[wm * 64 + mi * 16 + jj * 4 + i], s4);
            }
        }

        // ---- O += P.V  (V staged into Bs, 2 iters of 64 keys) ----
        const u16* pv[4];
#pragma unroll
        for (int r = 0; r < 4; ++r)
            pv[r] = vt + (long)(h * 128 + rrow[r]) * 4096 + bb * 512 + n0k + rgc[r] * 8;
        for (int kt = 0; kt < 2; ++kt) {
#pragma unroll
            for (int r = 0; r < 4; ++r) {
                gl_lds16(pv[r], dB + r * 2048);
                pv[r] += 64;
            }
            __syncthreads();
#pragma unroll
            for (int s = 0; s < 2; ++s) {
                bf16x8 af[4], bfr[4];
#pragma unroll
                for (int mi = 0; mi < 4; ++mi) {
                    int row = wm * 64 + mi * 16 + lr;
                    af[mi] = *(const bf16x8*)&Ps[row * 136 + kt * 64 + s * 32 + jj * 8];
                }
#pragma unroll
                for (int ni = 0; ni < 4; ++ni) {
                    int row  = wn * 64 + ni * 16 + lr;
                    int slot = (s * 4 + jj + row) & 7;
                    bfr[ni] = *(const bf16x8*)&Bs[row * 64 + slot * 8];
                }
#pragma unroll
                for (int mi = 0; mi < 4; ++mi)
#pragma unroll
                    for (int ni = 0; ni < 4; ++ni)
                        acc_o[mi][ni] = __builtin_amdgcn_mfma_f32_16x16x32_bf16(
                            af[mi], bfr[ni], acc_o[mi][ni], 0, 0, 0);
            }
            __syncthreads();
        }
    }

    // ---- epilogue: O / l, write o[bs][h*128 + vcol] ----
#pragma unroll
    for (int mi = 0; mi < 4; ++mi) {
#pragma unroll
        for (int i = 0; i < 4; ++i) {
            int row = wm * 64 + mi * 16 + jj * 4 + i;
            float linv = 1.0f / l_sum[row];
            long grow = (long)(bb * 512 + m0 + row) * 2048 + h * 128;
#pragma unroll
            for (int ni = 0; ni < 4; ++ni) {
                int colc = wn * 64 + ni * 16 + lr;
                o[grow + colc] = f2us(acc_o[mi][ni][i] * linv);
            }
        }
    }
}

// ---------------------------------------------------------------------------
// fp32 -> bf16 elementwise (vectorized x4)
// ---------------------------------------------------------------------------
__global__ __launch_bounds__(256)
void conv_f32_bf16(const float* __restrict__ in, u16* __restrict__ out)
{
    int i = blockIdx.x * 256 + threadIdx.x;
    float4 v = ((const float4*)in)[i];
    ushort4 o;
    o.x = f2us(v.x); o.y = f2us(v.y); o.z = f2us(v.z); o.w = f2us(v.w);
    ((ushort4*)out)[i] = o;
}

// ---------------------------------------------------------------------------
// ALL weight transposes fused in one dispatch: fp32 [K][N] -> bf16 [N][K],
// 32x32 LDS tiles, flat blockIdx decode over 4 groups (14336 tiles total).
// ---------------------------------------------------------------------------
struct TCAll {
    const float *Wdq, *Wdkv, *Wkr, *Wuq, *Wuk, *Wuv, *Wqr, *Wfc;
    u16 *Wc1, *Wc2, *Wqr_t, *Wfc_t;
};

__global__ __launch_bounds__(256)
void tconv_all(TCAll a)
{
    __shared__ float tile[32][33];
    const int bid = blockIdx.x;
    const float* in; u16* out; int K, N, nx, ny;
    if (bid < 3072) {               // Wc1: [Wdq|Wdkv|Wkr], K=2048 N=512
        int z = bid >> 10, rem = bid & 1023;
        in = z == 0 ? a.Wdq : (z == 1 ? a.Wdkv : a.Wkr);
        out = a.Wc1 + z * 1048576;
        K = 2048; N = 512; nx = rem & 15; ny = rem >> 4;
    } else if (bid < 6144) {        // Wc2: [Wuq|Wuk|Wuv], K=512 N=2048
        int l = bid - 3072, z = l >> 10, rem = l & 1023;
        in = z == 0 ? a.Wuq : (z == 1 ? a.Wuk : a.Wuv);
        out = a.Wc2 + z * 1048576;
        K = 512; N = 2048; nx = rem & 63; ny = rem >> 6;
    } else if (bid < 10240) {       // Wqr: K=512 N=8192
        int l = bid - 6144;
        in = a.Wqr; out = a.Wqr_t;
        K = 512; N = 8192; nx = l & 255; ny = l >> 8;
    } else {                        // Wfc: K=2048 N=2048
        int l = bid - 10240;
        in = a.Wfc; out = a.Wfc_t;
        K = 2048; N = 2048; nx = l & 63; ny = l >> 6;
    }
    const int n0 = nx * 32, k0 = ny * 32;
    const int c = threadIdx.x & 31, r0 = threadIdx.x >> 5;
#pragma unroll
    for (int j = 0; j < 4; ++j) {
        int r = r0 + j * 8;
        tile[r][c] = in[(long)(k0 + r) * N + n0 + c];
    }
    __syncthreads();
#pragma unroll
    for (int j = 0; j < 4; ++j) {
        int r = r0 + j * 8;
        out[(long)(n0 + r) * K + k0 + c] = f2us(tile[c][r]);
    }
}

// ---------------------------------------------------------------------------
// prep kernel: bias concat gather (blocks 0..61) + RoPE table fill
// (blocks 62..573: pos = bid-62, 256 threads = 256 col-pairs).
// tab[pos][i] = (cos(pos*f_i), sin(pos*f_i)), f_i = 10000^(-2i/512).
// ---------------------------------------------------------------------------
struct BG {
    const float *bdq, *bdkv, *bkr, *buq, *bqr, *buk, *buv;
    float *biasD, *biasQ, *biasK;
    float2* ropeTab;
};

__global__ __launch_bounds__(256)
void prep_misc(BG a)
{
    if (blockIdx.x >= 62) {
        int pos = blockIdx.x - 62;            // 0..511
        int i   = threadIdx.x;                // 0..255
        float f = __expf(-9.2103403719761836f * (float)(2 * i) * (1.0f / 512.0f));
        float s, c;
        __sincosf((float)pos * f, &s, &c);
        a.ropeTab[pos * 256 + i] = make_float2(c, s);
        return;
    }
    int i = blockIdx.x * 256 + threadIdx.x;   // 0 .. 15871
    if (i < 1536) {
        float v = i < 512 ? a.bdq[i] : (i < 1024 ? a.bdkv[i - 512] : a.bkr[i - 1024]);
        a.biasD[i] = v;
    } else if (i < 11776) {
        int j = i - 1536;
        a.biasQ[j] = j < 2048 ? a.buq[j] : a.bqr[j - 2048];
    } else {
        int j = i - 11776;
        a.biasK[j] = j < 2048 ? a.buk[j] : a.buv[j - 2048];
    }
}

// ---------------------------------------------------------------------------
extern "C" void kernel_launch(void* const* d_in, const int* in_sizes, int n_in,
                              void* d_out, int out_size, void* d_ws, size_t ws_size,
                              hipStream_t stream)
{
    (void)in_sizes; (void)n_in; (void)out_size; (void)ws_size;

    const float* X    = (const float*)d_in[0];
    const float* Wdq  = (const float*)d_in[1];  const float* bdq  = (const float*)d_in[2];
    const float* Wdkv = (const float*)d_in[3];  const float* bdkv = (const float*)d_in[4];
    const float* Wuq  = (const float*)d_in[5];  const float* buq  = (const float*)d_in[6];
    const float* Wuk  = (const float*)d_in[7];  const float* buk  = (const float*)d_in[8];
    const float* Wuv  = (const float*)d_in[9];  const float* buv  = (const float*)d_in[10];
    const float* Wqr  = (const float*)d_in[11]; const float* bqr  = (const float*)d_in[12];
    const float* Wkr  = (const float*)d_in[13]; const float* bkr  = (const float*)d_in[14];
    const float* Wfc  = (const float*)d_in[15]; const float* bfc  = (const float*)d_in[16];
    float* out = (float*)d_out;

    // workspace (u16 elems), ~185 MB + fp32 bias tail + 1MB rope table.
    u16* ws = (u16*)d_ws;
    u16* Xb     = ws;                 // [4096][2048]               8M
    u16* Wc1    = Xb   + 8388608;     // [Wdq_t|Wdkv_t|Wkr_t] = [1536][2048]  3M
    u16* Wc2    = Wc1  + 3145728;     // [Wuq_t|Wuk_t|Wuv_t]  = [6144][512]   3M
    u16* Wqr_t  = Wc2  + 3145728;     // [8192][512]                4M
    u16* Wfc_t  = Wqr_t + 4194304;    // [2048][2048]               4M
    u16* ckk    = Wfc_t + 4194304;    // [4096][1536] = c_q|c_kv|k_r  6M
    u16* q_c    = ckk  + 6291456;     // [4096][2048]               8M
    u16* k_c    = q_c  + 8388608;     // [4096][2048]               8M
    u16* v_t    = k_c  + 8388608;     // [2048][4096] (V^T)         8M
    u16* q_r    = v_t  + 8388608;     // [4096][8192]               32M
    u16* o      = q_r  + 33554432;    // [4096][2048]               8M
    float* biasD = (float*)(o + 8388608);   // 1536
    float* biasQ = biasD + 1536;            // 10240
    float* biasK = biasQ + 10240;           // 4096
    float2* ropeTab = (float2*)(biasK + 4096);   // [512][256] = 1 MB

    dim3 blk(256, 1, 1);

    // ---- converts + prep: 3 dispatches ----
    conv_f32_bf16<<<8192, blk, 0, stream>>>(X, Xb);
    {   TCAll a{Wdq, Wdkv, Wkr, Wuq, Wuk, Wuv, Wqr, Wfc,
                Wc1, Wc2, Wqr_t, Wfc_t};
        tconv_all<<<14336, blk, 0, stream>>>(a); }
    {   BG a{bdq, bdkv, bkr, buq, bqr, buk, buv, biasD, biasQ, biasK, ropeTab};
        prep_misc<<<574, blk, 0, stream>>>(a); }

    const int NOSPLIT = 1 << 30;

    {   // down-proj: ckk[4096][1536] = X @ [Wdq|Wdkv|Wkr] + bias, rope cols>=1024
        GArgs a{};
        a.A0 = Xb; a.B0 = Wc1; a.B0r2 = Wc1 + 2l * 1048576; a.K0 = 2048;
        a.bias = biasD; a.ropeTab = ropeTab; a.C = ckk; a.C2 = ckk + 1024;
        a.colSplit = 1024;
        gemm_mfma<2048, 2048, 1536, 1536, FLAG_ROPE2>
            <<<dim3(12, 32, 1), blk, 0, stream>>>(a);
    }
    {   // up-proj q: [q_c | q_r(rope)] = c_q @ [Wuq|Wqr] + bias
        GArgs a{};
        a.A0 = ckk; a.B0 = Wc2; a.B0r2 = Wqr_t; a.K0 = 512;
        a.bias = biasQ; a.ropeTab = ropeTab; a.C = q_c; a.C2 = q_r;
        a.colSplit = 2048;
        gemm_mfma<1536, 512, 2048, 8192, FLAG_ROPE2>
            <<<dim3(80, 32, 1), blk, 0, stream>>>(a);
    }
    {   // up-proj kv: [k_c | v^T] = c_kv @ [Wuk|Wuv] + bias
        GArgs a{};
        a.A0 = ckk + 512; a.B0 = Wc2 + 1048576; a.B0r2 = Wc2 + 2l * 1048576;
        a.K0 = 512;
        a.bias = biasK; a.ropeTab = ropeTab; a.C = k_c; a.C2 = v_t;
        a.colSplit = 2048;
        gemm_mfma<1536, 512, 2048, 4096, FLAG_TRANS2>
            <<<dim3(32, 32, 1), blk, 0, stream>>>(a);
    }

    // ---- fused attention: scores + softmax(C=0) + PV, no attn buffer ----
    attn_fused<<<dim3(4, 128, 1), blk, 0, stream>>>(
        q_c, k_c, q_r, ckk + 1024, v_t, o);

    // ---- final projection (fp32 out) ----
    {
        GArgs a{};
        a.A0 = o; a.B0 = Wfc_t; a.B0r2 = Wfc_t; a.K0 = 2048;
        a.bias = bfc; a.ropeTab = ropeTab; a.C = out; a.C2 = out;
        a.colSplit = NOSPLIT;
        gemm_mfma<2048, 2048, 2048, 1, FLAG_F32OUT>
            <<<dim3(16, 32, 1), blk, 0, stream>>>(a);
    }
}

// Round 9
// 417.648 us; speedup vs baseline: 1.1459x; 1.1459x over previous
//
#include <hip/hip_runtime.h>
#include <hip/hip_bf16.h>
#include <stdint.h>

typedef unsigned short u16;
typedef short bf16x8 __attribute__((ext_vector_type(8)));
typedef float f32x4 __attribute__((ext_vector_type(4)));

__device__ __forceinline__ float us2f(u16 u) {
    union { unsigned int i; float f; } x;
    x.i = ((unsigned int)u) << 16;
    return x.f;
}

__device__ __forceinline__ u16 f2us(float f) {
    union { float f; unsigned int i; } x; x.f = f;
    unsigned int lsb = (x.i >> 16) & 1u;
    x.i += 0x7FFFu + lsb;            // round-to-nearest-even
    return (u16)(x.i >> 16);
}

// async global->LDS, 16B per lane. LDS dest = wave-uniform base + lane*16.
__device__ __forceinline__ void gl_lds16(const u16* g, u16* l) {
    __builtin_amdgcn_global_load_lds(
        (const __attribute__((address_space(1))) void*)(uintptr_t)(const void*)g,
        (__attribute__((address_space(3))) void*)(uintptr_t)(void*)l,
        16, 0, 0);
}

#define FLAG_ROPE2  1   // region2 cols get interleaved RoPE (head_dim 512)
#define FLAG_TRANS2 4   // region2 written transposed (LDC2 = rows stride)
#define FLAG_F32OUT 8   // region1 written fp32

struct GArgs {
    const u16 *A0, *B0, *B0r2;
    int K0;
    const float* bias;          // indexed by global col (concatenated)
    void* C; void* C2;
    int colSplit;               // cols >= colSplit -> region2 (multiple of 128)
};

// ---------------------------------------------------------------------------
// NT MFMA GEMM: C[m,n] = sum_k A[m,k]*Bt[n,k]. 128x128 tile, BK=64,
// 256 threads = 4 waves 2x2, each wave 64x64 (4x4 MFMA subtiles).
// bf16 in (K-major both sides), fp32 accum. Column-split epilogue: cols >=
// colSplit go to C2 (optionally RoPE'd or transposed), B rows from B0r2.
// LDS rotation: slot s of row r holds chunk (s - r) & 7 (measured 0 confl).
// RoPE epilogue: incremental sincos (r5-measured best; r8's table version
// regressed 82.7->127.7 us - latency-bound table loads at 19% occupancy).
// ---------------------------------------------------------------------------
template <int LDA0, int LDB0, int LDC, int LDC2, int FLAGS>
__global__ __launch_bounds__(256)
void gemm_mfma(GArgs g)
{
    __shared__ u16 As[128 * 64];   // 16 KB
    __shared__ u16 Bs[128 * 64];   // 16 KB

    const int t    = threadIdx.x;
    const int lane = t & 63;
    const int w    = t >> 6;
    const int wm   = w >> 1, wn = w & 1;
    const int m0   = blockIdx.y * 128;
    const int n0   = blockIdx.x * 128;
    const bool r2  = (n0 >= g.colSplit);

    const int srow = t >> 3;    // 0..31 base row for staging
    const int sp   = t & 7;     // LDS slot within row
    u16* dA = As + t * 8;
    u16* dB = Bs + t * 8;

    const int lr = lane & 15;
    const int jj = lane >> 4;

    f32x4 acc[4][4];
#pragma unroll
    for (int i = 0; i < 4; ++i)
#pragma unroll
        for (int j = 0; j < 4; ++j)
            acc[i][j] = (f32x4){0.f, 0.f, 0.f, 0.f};

    {
        const u16* A = g.A0;
        const u16* B = r2 ? g.B0r2 - (long)g.colSplit * LDB0 : g.B0;
        const u16* gA[4];
        const u16* gB[4];
#pragma unroll
        for (int r = 0; r < 4; ++r) {
            int row = r * 32 + srow;
            int gc  = (sp - row) & 7;
            gA[r] = A + (long)(m0 + row) * LDA0 + gc * 8;
            gB[r] = B + (long)(n0 + row) * LDB0 + gc * 8;
        }
        for (int kt = 0; kt < g.K0; kt += 64) {
#pragma unroll
            for (int r = 0; r < 4; ++r) {
                gl_lds16(gA[r], dA + r * 2048);
                gl_lds16(gB[r], dB + r * 2048);
                gA[r] += 64; gB[r] += 64;
            }
            __syncthreads();
#pragma unroll
            for (int s = 0; s < 2; ++s) {
                bf16x8 af[4], bfr[4];
#pragma unroll
                for (int mi = 0; mi < 4; ++mi) {
                    int row  = wm * 64 + mi * 16 + lr;
                    int slot = (s * 4 + jj + row) & 7;
                    af[mi] = *(const bf16x8*)&As[row * 64 + slot * 8];
                }
#pragma unroll
                for (int ni = 0; ni < 4; ++ni) {
                    int row  = wn * 64 + ni * 16 + lr;
                    int slot = (s * 4 + jj + row) & 7;
                    bfr[ni] = *(const bf16x8*)&Bs[row * 64 + slot * 8];
                }
#pragma unroll
                for (int mi = 0; mi < 4; ++mi)
#pragma unroll
                    for (int ni = 0; ni < 4; ++ni)
                        acc[mi][ni] = __builtin_amdgcn_mfma_f32_16x16x32_bf16(
                            af[mi], bfr[ni], acc[mi][ni], 0, 0, 0);
            }
            __syncthreads();
        }
    }

    // epilogue. C/D layout: col = lane&15, row = (lane>>4)*4 + reg.
    const int eCol0 = n0 + wn * 64 + lr;
    const int eRow0 = m0 + wm * 64 + jj * 4;
    const bool oddc = lane & 1;

    if (g.bias) {
#pragma unroll
        for (int ni = 0; ni < 4; ++ni) {
            float bv = g.bias[eCol0 + ni * 16];
#pragma unroll
            for (int mi = 0; mi < 4; ++mi) {
                acc[mi][ni][0] += bv; acc[mi][ni][1] += bv;
                acc[mi][ni][2] += bv; acc[mi][ni][3] += bv;
            }
        }
    }

    if (!r2) {
#pragma unroll
        for (int mi = 0; mi < 4; ++mi)
#pragma unroll
            for (int ni = 0; ni < 4; ++ni) {
                int rowb = eRow0 + mi * 16;
                int colg = eCol0 + ni * 16;
                if (FLAGS & FLAG_F32OUT) {
                    float* cp = (float*)g.C;
#pragma unroll
                    for (int i = 0; i < 4; ++i)
                        cp[(long)(rowb + i) * LDC + colg] = acc[mi][ni][i];
                } else {
                    u16* cp = (u16*)g.C;
#pragma unroll
                    for (int i = 0; i < 4; ++i)
                        cp[(long)(rowb + i) * LDC + colg] = f2us(acc[mi][ni][i]);
                }
            }
    } else if (FLAGS & FLAG_ROPE2) {
        // incremental-rotation RoPE: per ni only 3 sincos; rows within a
        // block never wrap mod 512 (m0%512 in {0,128,256,384}).
        const float base_s = (float)(eRow0 & 511);
#pragma unroll
        for (int ni = 0; ni < 4; ++ni) {
            int col2 = eCol0 + ni * 16 - g.colSplit;
            int rp   = (col2 & 511) & ~1;
            float f  = __expf(-9.2103403719761836f * (float)rp * (1.0f / 512.0f));
            float s1, c1, s16, c16, sb, cb;
            __sincosf(f, &s1, &c1);
            __sincosf(16.0f * f, &s16, &c16);
            __sincosf(base_s * f, &sb, &cb);
            float cm = cb, sm = sb;          // angle at row eRow0 + mi*16
#pragma unroll
            for (int mi = 0; mi < 4; ++mi) {
                f32x4 v = acc[mi][ni];
                float cr = cm, sr = sm;      // angle at current row
#pragma unroll
                for (int i = 0; i < 4; ++i) {
                    float other = __shfl_xor(v[i], 1, 64);
                    v[i] = oddc ? (v[i] * cr + other * sr)
                                : (v[i] * cr - other * sr);
                    float cn = cr * c1 - sr * s1;   // step +1 row
                    sr = sr * c1 + cr * s1; cr = cn;
                }
                int rowb = eRow0 + mi * 16;
                u16* cp = (u16*)g.C2;
#pragma unroll
                for (int i = 0; i < 4; ++i)
                    cp[(long)(rowb + i) * LDC2 + col2] = f2us(v[i]);
                float cn = cm * c16 - sm * s16;     // step +16 rows
                sm = sm * c16 + cm * s16; cm = cn;
            }
        }
    } else {
#pragma unroll
        for (int mi = 0; mi < 4; ++mi)
#pragma unroll
            for (int ni = 0; ni < 4; ++ni) {
                int rowb = eRow0 + mi * 16;
                int col2 = eCol0 + ni * 16 - g.colSplit;
                if (FLAGS & FLAG_TRANS2) {
                    u16* cp = (u16*)g.C2 + (long)col2 * LDC2 + rowb;
                    ushort4 o4;
                    o4.x = f2us(acc[mi][ni][0]); o4.y = f2us(acc[mi][ni][1]);
                    o4.z = f2us(acc[mi][ni][2]); o4.w = f2us(acc[mi][ni][3]);
                    *(ushort4*)cp = o4;
                } else {
                    u16* cp = (u16*)g.C2;
#pragma unroll
                    for (int i = 0; i < 4; ++i)
                        cp[(long)(rowb + i) * LDC2 + col2] = f2us(acc[mi][ni][i]);
                }
            }
    }
}

// ---------------------------------------------------------------------------
// Merged up-proj dispatch (r9): q-GEMM (2560 blocks, rope epilogue) and
// kv-GEMM (1024 blocks, transpose epilogue) interleaved 5:2 in groups of 7
// (3584 = 7*512 exactly, bijective). Mechanism: co-resident CU blocks mix
// VALU-heavy rope epilogues with MFMA/store-heavy kv blocks -> pipe overlap
// (m114), instead of all waves hitting the same phase in lockstep.
// Shared geometry hardcoded: LDA=1536, LDB=512, K0=512, LDC=2048,
// colSplit=2048. q: LDC2=8192 rope; kv: LDC2=4096 transpose.
// ---------------------------------------------------------------------------
struct U2 { GArgs q; GArgs kv; };

__global__ __launch_bounds__(256)
void gemm_up2(U2 u)
{
    __shared__ u16 As[128 * 64];   // 16 KB
    __shared__ u16 Bs[128 * 64];   // 16 KB

    const int fl = blockIdx.x;                 // 0..3583
    const int gi = fl / 7, ri = fl - gi * 7;   // group / rank
    const bool isQ = ri < 5;
    const int idx  = isQ ? gi * 5 + ri : gi * 2 + (ri - 5);
    int m0, n0;
    if (isQ) { n0 = (idx % 80) * 128; m0 = (idx / 80) * 128; }
    else     { n0 = (idx & 31) * 128; m0 = (idx >> 5) * 128; }
    const GArgs g = isQ ? u.q : u.kv;
    const bool r2 = (n0 >= 2048);

    const int t    = threadIdx.x;
    const int lane = t & 63;
    const int w    = t >> 6;
    const int wm   = w >> 1, wn = w & 1;

    const int srow = t >> 3;
    const int sp   = t & 7;
    u16* dA = As + t * 8;
    u16* dB = Bs + t * 8;

    const int lr = lane & 15;
    const int jj = lane >> 4;

    f32x4 acc[4][4];
#pragma unroll
    for (int i = 0; i < 4; ++i)
#pragma unroll
        for (int j = 0; j < 4; ++j)
            acc[i][j] = (f32x4){0.f, 0.f, 0.f, 0.f};

    {
        const u16* A = g.A0;
        const u16* B = r2 ? g.B0r2 - 2048l * 512 : g.B0;
        const u16* gA[4];
        const u16* gB[4];
#pragma unroll
        for (int r = 0; r < 4; ++r) {
            int row = r * 32 + srow;
            int gc  = (sp - row) & 7;
            gA[r] = A + (long)(m0 + row) * 1536 + gc * 8;
            gB[r] = B + (long)(n0 + row) * 512 + gc * 8;
        }
#pragma unroll 1
        for (int kt = 0; kt < 512; kt += 64) {
#pragma unroll
            for (int r = 0; r < 4; ++r) {
                gl_lds16(gA[r], dA + r * 2048);
                gl_lds16(gB[r], dB + r * 2048);
                gA[r] += 64; gB[r] += 64;
            }
            __syncthreads();
#pragma unroll
            for (int s = 0; s < 2; ++s) {
                bf16x8 af[4], bfr[4];
#pragma unroll
                for (int mi = 0; mi < 4; ++mi) {
                    int row  = wm * 64 + mi * 16 + lr;
                    int slot = (s * 4 + jj + row) & 7;
                    af[mi] = *(const bf16x8*)&As[row * 64 + slot * 8];
                }
#pragma unroll
                for (int ni = 0; ni < 4; ++ni) {
                    int row  = wn * 64 + ni * 16 + lr;
                    int slot = (s * 4 + jj + row) & 7;
                    bfr[ni] = *(const bf16x8*)&Bs[row * 64 + slot * 8];
                }
#pragma unroll
                for (int mi = 0; mi < 4; ++mi)
#pragma unroll
                    for (int ni = 0; ni < 4; ++ni)
                        acc[mi][ni] = __builtin_amdgcn_mfma_f32_16x16x32_bf16(
                            af[mi], bfr[ni], acc[mi][ni], 0, 0, 0);
            }
            __syncthreads();
        }
    }

    const int eCol0 = n0 + wn * 64 + lr;
    const int eRow0 = m0 + wm * 64 + jj * 4;
    const bool oddc = lane & 1;

#pragma unroll
    for (int ni = 0; ni < 4; ++ni) {
        float bv = g.bias[eCol0 + ni * 16];
#pragma unroll
        for (int mi = 0; mi < 4; ++mi) {
            acc[mi][ni][0] += bv; acc[mi][ni][1] += bv;
            acc[mi][ni][2] += bv; acc[mi][ni][3] += bv;
        }
    }

    if (!r2) {
        // region1: plain bf16, LDC=2048 (q_c or k_c)
        u16* cp = (u16*)g.C;
#pragma unroll
        for (int mi = 0; mi < 4; ++mi)
#pragma unroll
            for (int ni = 0; ni < 4; ++ni) {
                int rowb = eRow0 + mi * 16;
                int colg = eCol0 + ni * 16;
#pragma unroll
                for (int i = 0; i < 4; ++i)
                    cp[(long)(rowb + i) * 2048 + colg] = f2us(acc[mi][ni][i]);
            }
    } else if (isQ) {
        // rope region2 -> q_r, LDC2=8192 (incremental sincos, r5-verified)
        const float base_s = (float)(eRow0 & 511);
#pragma unroll
        for (int ni = 0; ni < 4; ++ni) {
            int col2 = eCol0 + ni * 16 - 2048;
            int rp   = (col2 & 511) & ~1;
            float f  = __expf(-9.2103403719761836f * (float)rp * (1.0f / 512.0f));
            float s1, c1, s16, c16, sb, cb;
            __sincosf(f, &s1, &c1);
            __sincosf(16.0f * f, &s16, &c16);
            __sincosf(base_s * f, &sb, &cb);
            float cm = cb, sm = sb;
#pragma unroll
            for (int mi = 0; mi < 4; ++mi) {
                f32x4 v = acc[mi][ni];
                float cr = cm, sr = sm;
#pragma unroll
                for (int i = 0; i < 4; ++i) {
                    float other = __shfl_xor(v[i], 1, 64);
                    v[i] = oddc ? (v[i] * cr + other * sr)
                                : (v[i] * cr - other * sr);
                    float cn = cr * c1 - sr * s1;
                    sr = sr * c1 + cr * s1; cr = cn;
                }
                int rowb = eRow0 + mi * 16;
                u16* cp = (u16*)g.C2;
#pragma unroll
                for (int i = 0; i < 4; ++i)
                    cp[(long)(rowb + i) * 8192 + col2] = f2us(v[i]);
                float cn = cm * c16 - sm * s16;
                sm = sm * c16 + cm * s16; cm = cn;
            }
        }
    } else {
        // transpose region2 -> v_t, LDC2=4096
#pragma unroll
        for (int mi = 0; mi < 4; ++mi)
#pragma unroll
            for (int ni = 0; ni < 4; ++ni) {
                int rowb = eRow0 + mi * 16;
                int col2 = eCol0 + ni * 16 - 2048;
                u16* cp = (u16*)g.C2 + (long)col2 * 4096 + rowb;
                ushort4 o4;
                o4.x = f2us(acc[mi][ni][0]); o4.y = f2us(acc[mi][ni][1]);
                o4.z = f2us(acc[mi][ni][2]); o4.w = f2us(acc[mi][ni][3]);
                *(ushort4*)cp = o4;
            }
    }
}

// ---------------------------------------------------------------------------
// Fused attention (round-5 verbatim: best measured 82.5 us, 524K confl).
// per block = (b, h, 128 q-rows). Loops 4 key-tiles of 128:
//   S = qc.kc^T (K=128) + qr.kr^T (K=512)   [BK=64 staged, MFMA]
//   P = exp(S*scale) -> Ps (stride 136); l_sum partials (LDS atomics)
//   O += P.V  (V staged into Bs, 2 halves)
// XCD swizzle: 4 q-tile sharers of one z on the same XCD; bb = xcd
// (r5-measured FETCH 246->183 MB).
// ---------------------------------------------------------------------------
__global__ __launch_bounds__(256, 2)
void attn_fused(const u16* __restrict__ qc, const u16* __restrict__ kc,
                const u16* __restrict__ qr, const u16* __restrict__ kr,
                const u16* __restrict__ vt, u16* __restrict__ o)
{
    __shared__ u16 As[128 * 64];       // 16 KB  (BK=64)
    __shared__ u16 Bs[128 * 64];       // 16 KB
    __shared__ u16 Ps[128 * 136];      // 34 KB (pad 128->136 for banks)
    __shared__ float l_sum[128];

    const int t    = threadIdx.x;
    const int lane = t & 63;
    const int w    = t >> 6;
    const int wm   = w >> 1, wn = w & 1;

    const int flat = blockIdx.x + (blockIdx.y << 2);   // hw dispatch order
    const int xcd  = flat & 7;
    const int j    = flat >> 3;                        // 0..63
    const int m0   = (j >> 4) * 128;
    const int z    = xcd * 16 + (j & 15);              // 0..127
    const int bb   = z >> 4, h = z & 15;

    if (t < 128) l_sum[t] = 0.f;

    const int srow = t >> 3;
    const int sp   = t & 7;
    u16* dA = As + t * 8;
    u16* dB = Bs + t * 8;
    int rrow[4], rgc[4];
#pragma unroll
    for (int r = 0; r < 4; ++r) {
        rrow[r] = r * 32 + srow;
        rgc[r]  = (sp - rrow[r]) & 7;
    }

    const int lr = lane & 15;
    const int jj = lane >> 4;

    const u16* gqc[4];
    const u16* gqr[4];
#pragma unroll
    for (int r = 0; r < 4; ++r) {
        gqc[r] = qc + (long)(bb * 512 + m0 + rrow[r]) * 2048 + h * 128 + rgc[r] * 8;
        gqr[r] = qr + (long)(bb * 512 + m0 + rrow[r]) * 8192 + h * 512 + rgc[r] * 8;
    }

    f32x4 acc_o[4][4];
#pragma unroll
    for (int i = 0; i < 4; ++i)
#pragma unroll
        for (int j2 = 0; j2 < 4; ++j2) acc_o[i][j2] = (f32x4){0.f, 0.f, 0.f, 0.f};

    const float scale = 1.0f / 33.941125496954285f;   // 1/(sqrt(128)+sqrt(512))

    for (int nt = 0; nt < 4; ++nt) {
        const int n0k = nt * 128;

        f32x4 acc_s[4][4];
#pragma unroll
        for (int i = 0; i < 4; ++i)
#pragma unroll
            for (int j2 = 0; j2 < 4; ++j2) acc_s[i][j2] = (f32x4){0.f, 0.f, 0.f, 0.f};

        const u16* pa[4];
        const u16* pb[4];
#pragma unroll
        for (int r = 0; r < 4; ++r) {
            pa[r] = gqc[r];
            pb[r] = kc + (long)(bb * 512 + n0k + rrow[r]) * 2048 + h * 128 + rgc[r] * 8;
        }
        for (int seg = 0; seg < 2; ++seg) {
            int iters = seg == 0 ? 2 : 8;        // K=128, then K=512
            for (int kt = 0; kt < iters; ++kt) {
#pragma unroll
                for (int r = 0; r < 4; ++r) {
                    gl_lds16(pa[r], dA + r * 2048);
                    gl_lds16(pb[r], dB + r * 2048);
                    pa[r] += 64; pb[r] += 64;
                }
                __syncthreads();
#pragma unroll
                for (int s = 0; s < 2; ++s) {
                    bf16x8 af[4], bfr[4];
#pragma unroll
                    for (int mi = 0; mi < 4; ++mi) {
                        int row  = wm * 64 + mi * 16 + lr;
                        int slot = (s * 4 + jj + row) & 7;
                        af[mi] = *(const bf16x8*)&As[row * 64 + slot * 8];
                    }
#pragma unroll
                    for (int ni = 0; ni < 4; ++ni) {
                        int row  = wn * 64 + ni * 16 + lr;
                        int slot = (s * 4 + jj + row) & 7;
                        bfr[ni] = *(const bf16x8*)&Bs[row * 64 + slot * 8];
                    }
#pragma unroll
                    for (int mi = 0; mi < 4; ++mi)
#pragma unroll
                        for (int ni = 0; ni < 4; ++ni)
                            acc_s[mi][ni] = __builtin_amdgcn_mfma_f32_16x16x32_bf16(
                                af[mi], bfr[ni], acc_s[mi][ni], 0, 0, 0);
                }
                __syncthreads();
            }
            if (seg == 0) {
#pragma unroll
                for (int r = 0; r < 4; ++r) {
                    pa[r] = gqr[r];
                    pb[r] = kr + (long)(bb * 512 + n0k + rrow[r]) * 1536 + rgc[r] * 8;
                }
            }
        }

        // ---- P = exp(S*scale) -> Ps; l partial sums -> l_sum ----
#pragma unroll
        for (int mi = 0; mi < 4; ++mi) {
            float rowpart[4] = {0.f, 0.f, 0.f, 0.f};
#pragma unroll
            for (int ni = 0; ni < 4; ++ni) {
                f32x4 v = acc_s[mi][ni];
                int colP = wn * 64 + ni * 16 + lr;
#pragma unroll
                for (int i = 0; i < 4; ++i) {
                    float e = __expf(v[i] * scale);
                    rowpart[i] += e;
                    int rowP = wm * 64 + mi * 16 + jj * 4 + i;
                    Ps[rowP * 136 + colP] = f2us(e);
                }
            }
#pragma unroll
            for (int i = 0; i < 4; ++i) {
                float s4 = rowpart[i];
                s4 += __shfl_xor(s4, 1, 64);
                s4 += __shfl_xor(s4, 2, 64);
                s4 += __shfl_xor(s4, 4, 64);
                s4 += __shfl_xor(s4, 8, 64);
                if ((lane & 15) == 0)
                    atomicAdd(&l_sum[wm * 64 + mi * 16 + jj * 4 + i], s4);
            }
        }

        // ---- O += P.V  (V staged into Bs, 2 iters of 64 keys) ----
        const u16* pv[4];
#pragma unroll
        for (int r = 0; r < 4; ++r)
            pv[r] = vt + (long)(h * 128 + rrow[r]) * 4096 + bb * 512 + n0k + rgc[r] * 8;
        for (int kt = 0; kt < 2; ++kt) {
#pragma unroll
            for (int r = 0; r < 4; ++r) {
                gl_lds16(pv[r], dB + r * 2048);
                pv[r] += 64;
            }
            __syncthreads();
#pragma unroll
            for (int s = 0; s < 2; ++s) {
                bf16x8 af[4], bfr[4];
#pragma unroll
                for (int mi = 0; mi < 4; ++mi) {
                    int row = wm * 64 + mi * 16 + lr;
                    af[mi] = *(const bf16x8*)&Ps[row * 136 + kt * 64 + s * 32 + jj * 8];
                }
#pragma unroll
                for (int ni = 0; ni < 4; ++ni) {
                    int row  = wn * 64 + ni * 16 + lr;
                    int slot = (s * 4 + jj + row) & 7;
                    bfr[ni] = *(const bf16x8*)&Bs[row * 64 + slot * 8];
                }
#pragma unroll
                for (int mi = 0; mi < 4; ++mi)
#pragma unroll
                    for (int ni = 0; ni < 4; ++ni)
                        acc_o[mi][ni] = __builtin_amdgcn_mfma_f32_16x16x32_bf16(
                            af[mi], bfr[ni], acc_o[mi][ni], 0, 0, 0);
            }
            __syncthreads();
        }
    }

    // ---- epilogue: O / l, write o[bs][h*128 + vcol] ----
#pragma unroll
    for (int mi = 0; mi < 4; ++mi) {
#pragma unroll
        for (int i = 0; i < 4; ++i) {
            int row = wm * 64 + mi * 16 + jj * 4 + i;
            float linv = 1.0f / l_sum[row];
            long grow = (long)(bb * 512 + m0 + row) * 2048 + h * 128;
#pragma unroll
            for (int ni = 0; ni < 4; ++ni) {
                int colc = wn * 64 + ni * 16 + lr;
                o[grow + colc] = f2us(acc_o[mi][ni][i] * linv);
            }
        }
    }
}

// ---------------------------------------------------------------------------
// fp32 -> bf16 elementwise (vectorized x4)
// ---------------------------------------------------------------------------
__global__ __launch_bounds__(256)
void conv_f32_bf16(const float* __restrict__ in, u16* __restrict__ out)
{
    int i = blockIdx.x * 256 + threadIdx.x;
    float4 v = ((const float4*)in)[i];
    ushort4 o;
    o.x = f2us(v.x); o.y = f2us(v.y); o.z = f2us(v.z); o.w = f2us(v.w);
    ((ushort4*)out)[i] = o;
}

// ---------------------------------------------------------------------------
// ALL weight transposes fused in one dispatch: fp32 [K][N] -> bf16 [N][K],
// 32x32 LDS tiles, flat blockIdx decode over 4 groups (14336 tiles total).
// ---------------------------------------------------------------------------
struct TCAll {
    const float *Wdq, *Wdkv, *Wkr, *Wuq, *Wuk, *Wuv, *Wqr, *Wfc;
    u16 *Wc1, *Wc2, *Wqr_t, *Wfc_t;
};

__global__ __launch_bounds__(256)
void tconv_all(TCAll a)
{
    __shared__ float tile[32][33];
    const int bid = blockIdx.x;
    const float* in; u16* out; int K, N, nx, ny;
    if (bid < 3072) {               // Wc1: [Wdq|Wdkv|Wkr], K=2048 N=512
        int z = bid >> 10, rem = bid & 1023;
        in = z == 0 ? a.Wdq : (z == 1 ? a.Wdkv : a.Wkr);
        out = a.Wc1 + z * 1048576;
        K = 2048; N = 512; nx = rem & 15; ny = rem >> 4;
    } else if (bid < 6144) {        // Wc2: [Wuq|Wuk|Wuv], K=512 N=2048
        int l = bid - 3072, z = l >> 10, rem = l & 1023;
        in = z == 0 ? a.Wuq : (z == 1 ? a.Wuk : a.Wuv);
        out = a.Wc2 + z * 1048576;
        K = 512; N = 2048; nx = rem & 63; ny = rem >> 6;
    } else if (bid < 10240) {       // Wqr: K=512 N=8192
        int l = bid - 6144;
        in = a.Wqr; out = a.Wqr_t;
        K = 512; N = 8192; nx = l & 255; ny = l >> 8;
    } else {                        // Wfc: K=2048 N=2048
        int l = bid - 10240;
        in = a.Wfc; out = a.Wfc_t;
        K = 2048; N = 2048; nx = l & 63; ny = l >> 6;
    }
    const int n0 = nx * 32, k0 = ny * 32;
    const int c = threadIdx.x & 31, r0 = threadIdx.x >> 5;
#pragma unroll
    for (int j = 0; j < 4; ++j) {
        int r = r0 + j * 8;
        tile[r][c] = in[(long)(k0 + r) * N + n0 + c];
    }
    __syncthreads();
#pragma unroll
    for (int j = 0; j < 4; ++j) {
        int r = r0 + j * 8;
        out[(long)(n0 + r) * K + k0 + c] = f2us(tile[c][r]);
    }
}

// ---------------------------------------------------------------------------
// bias concat gather: one dispatch replaces 7 tiny d2d memcpies.
// biasD=[bdq|bdkv|bkr] (1536), biasQ=[buq|bqr] (10240), biasK=[buk|buv] (4096)
// ---------------------------------------------------------------------------
struct BG {
    const float *bdq, *bdkv, *bkr, *buq, *bqr, *buk, *buv;
    float *biasD, *biasQ, *biasK;
};

__global__ __launch_bounds__(256)
void bias_gather(BG a)
{
    int i = blockIdx.x * 256 + threadIdx.x;   // 0 .. 15871
    if (i < 1536) {
        float v = i < 512 ? a.bdq[i] : (i < 1024 ? a.bdkv[i - 512] : a.bkr[i - 1024]);
        a.biasD[i] = v;
    } else if (i < 11776) {
        int j = i - 1536;
        a.biasQ[j] = j < 2048 ? a.buq[j] : a.bqr[j - 2048];
    } else {
        int j = i - 11776;
        a.biasK[j] = j < 2048 ? a.buk[j] : a.buv[j - 2048];
    }
}

// ---------------------------------------------------------------------------
extern "C" void kernel_launch(void* const* d_in, const int* in_sizes, int n_in,
                              void* d_out, int out_size, void* d_ws, size_t ws_size,
                              hipStream_t stream)
{
    (void)in_sizes; (void)n_in; (void)out_size; (void)ws_size;

    const float* X    = (const float*)d_in[0];
    const float* Wdq  = (const float*)d_in[1];  const float* bdq  = (const float*)d_in[2];
    const float* Wdkv = (const float*)d_in[3];  const float* bdkv = (const float*)d_in[4];
    const float* Wuq  = (const float*)d_in[5];  const float* buq  = (const float*)d_in[6];
    const float* Wuk  = (const float*)d_in[7];  const float* buk  = (const float*)d_in[8];
    const float* Wuv  = (const float*)d_in[9];  const float* buv  = (const float*)d_in[10];
    const float* Wqr  = (const float*)d_in[11]; const float* bqr  = (const float*)d_in[12];
    const float* Wkr  = (const float*)d_in[13]; const float* bkr  = (const float*)d_in[14];
    const float* Wfc  = (const float*)d_in[15]; const float* bfc  = (const float*)d_in[16];
    float* out = (float*)d_out;

    // workspace (u16 elems), ~184 MB + small fp32 bias tail. No attn buffer.
    u16* ws = (u16*)d_ws;
    u16* Xb     = ws;                 // [4096][2048]               8M
    u16* Wc1    = Xb   + 8388608;     // [Wdq_t|Wdkv_t|Wkr_t] = [1536][2048]  3M
    u16* Wc2    = Wc1  + 3145728;     // [Wuq_t|Wuk_t|Wuv_t]  = [6144][512]   3M
    u16* Wqr_t  = Wc2  + 3145728;     // [8192][512]                4M
    u16* Wfc_t  = Wqr_t + 4194304;    // [2048][2048]               4M
    u16* ckk    = Wfc_t + 4194304;    // [4096][1536] = c_q|c_kv|k_r  6M
    u16* q_c    = ckk  + 6291456;     // [4096][2048]               8M
    u16* k_c    = q_c  + 8388608;     // [4096][2048]               8M
    u16* v_t    = k_c  + 8388608;     // [2048][4096] (V^T)         8M
    u16* q_r    = v_t  + 8388608;     // [4096][8192]               32M
    u16* o      = q_r  + 33554432;    // [4096][2048]               8M
    float* biasD = (float*)(o + 8388608);   // 1536
    float* biasQ = biasD + 1536;            // 10240
    float* biasK = biasQ + 10240;           // 4096

    dim3 blk(256, 1, 1);

    // ---- converts: 3 dispatches total ----
    conv_f32_bf16<<<8192, blk, 0, stream>>>(X, Xb);
    {   TCAll a{Wdq, Wdkv, Wkr, Wuq, Wuk, Wuv, Wqr, Wfc,
                Wc1, Wc2, Wqr_t, Wfc_t};
        tconv_all<<<14336, blk, 0, stream>>>(a); }
    {   BG a{bdq, bdkv, bkr, buq, bqr, buk, buv, biasD, biasQ, biasK};
        bias_gather<<<62, blk, 0, stream>>>(a); }

    const int NOSPLIT = 1 << 30;

    {   // down-proj: ckk[4096][1536] = X @ [Wdq|Wdkv|Wkr] + bias, rope cols>=1024
        GArgs a{};
        a.A0 = Xb; a.B0 = Wc1; a.B0r2 = Wc1 + 2l * 1048576; a.K0 = 2048;
        a.bias = biasD; a.C = ckk; a.C2 = ckk + 1024;
        a.colSplit = 1024;
        gemm_mfma<2048, 2048, 1536, 1536, FLAG_ROPE2>
            <<<dim3(12, 32, 1), blk, 0, stream>>>(a);
    }
    {   // merged up-proj: [q_c|q_r(rope)] and [k_c|v^T] in one dispatch
        U2 u{};
        u.q.A0 = ckk; u.q.B0 = Wc2; u.q.B0r2 = Wqr_t; u.q.K0 = 512;
        u.q.bias = biasQ; u.q.C = q_c; u.q.C2 = q_r; u.q.colSplit = 2048;
        u.kv.A0 = ckk + 512; u.kv.B0 = Wc2 + 1048576;
        u.kv.B0r2 = Wc2 + 2l * 1048576; u.kv.K0 = 512;
        u.kv.bias = biasK; u.kv.C = k_c; u.kv.C2 = v_t; u.kv.colSplit = 2048;
        gemm_up2<<<3584, blk, 0, stream>>>(u);
    }

    // ---- fused attention: scores + softmax(C=0) + PV, no attn buffer ----
    attn_fused<<<dim3(4, 128, 1), blk, 0, stream>>>(
        q_c, k_c, q_r, ckk + 1024, v_t, o);

    // ---- final projection (fp32 out) ----
    {
        GArgs a{};
        a.A0 = o; a.B0 = Wfc_t; a.B0r2 = Wfc_t; a.K0 = 2048;
        a.bias = bfc; a.C = out; a.C2 = out;
        a.colSplit = NOSPLIT;
        gemm_mfma<2048, 2048, 2048, 1, FLAG_F32OUT>
            <<<dim3(16, 32, 1), blk, 0, stream>>>(a);
    }
}

// Round 10
// 415.920 us; speedup vs baseline: 1.1507x; 1.0042x over previous
//
#include <hip/hip_runtime.h>
#include <hip/hip_bf16.h>
#include <stdint.h>

typedef unsigned short u16;
typedef short bf16x8 __attribute__((ext_vector_type(8)));
typedef float f32x4 __attribute__((ext_vector_type(4)));

__device__ __forceinline__ float us2f(u16 u) {
    union { unsigned int i; float f; } x;
    x.i = ((unsigned int)u) << 16;
    return x.f;
}

__device__ __forceinline__ u16 f2us(float f) {
    union { float f; unsigned int i; } x; x.f = f;
    unsigned int lsb = (x.i >> 16) & 1u;
    x.i += 0x7FFFu + lsb;            // round-to-nearest-even
    return (u16)(x.i >> 16);
}

// async global->LDS, 16B per lane. LDS dest = wave-uniform base + lane*16.
__device__ __forceinline__ void gl_lds16(const u16* g, u16* l) {
    __builtin_amdgcn_global_load_lds(
        (const __attribute__((address_space(1))) void*)(uintptr_t)(const void*)g,
        (__attribute__((address_space(3))) void*)(uintptr_t)(void*)l,
        16, 0, 0);
}

// chain-free RoPE angle tables (r10): 3 sincos + short double/triple-angle
// chains; every element's (cos,sin) then = 2 INDEPENDENT fma (no 20-step
// serial recurrence). angles theta(mi,i) = (base_s + 16*mi + i) * f.
__device__ __forceinline__ void rope_cs(float f, float base_s,
                                        float (&Cm)[4], float (&Sm)[4],
                                        float (&ci)[4], float (&si)[4])
{
    float s1, c1, s16, c16, sb, cb;
    __sincosf(f, &s1, &c1);
    __sincosf(16.0f * f, &s16, &c16);
    __sincosf(base_s * f, &sb, &cb);
    ci[0] = 1.f; si[0] = 0.f;
    ci[1] = c1;  si[1] = s1;
    ci[2] = c1 * c1 - s1 * s1;          si[2] = 2.f * s1 * c1;
    ci[3] = ci[2] * c1 - si[2] * s1;    si[3] = si[2] * c1 + ci[2] * s1;
    Cm[0] = cb; Sm[0] = sb;
    Cm[1] = cb * c16 - sb * s16;        Sm[1] = sb * c16 + cb * s16;
    Cm[2] = Cm[1] * c16 - Sm[1] * s16;  Sm[2] = Sm[1] * c16 + Cm[1] * s16;
    Cm[3] = Cm[2] * c16 - Sm[2] * s16;  Sm[3] = Sm[2] * c16 + Cm[2] * s16;
}

#define FLAG_ROPE2  1   // region2 cols get interleaved RoPE (head_dim 512)
#define FLAG_TRANS2 4   // region2 written transposed (LDC2 = rows stride)
#define FLAG_F32OUT 8   // region1 written fp32

struct GArgs {
    const u16 *A0, *B0, *B0r2;
    int K0;
    const float* bias;          // indexed by global col (concatenated)
    void* C; void* C2;
    int colSplit;               // cols >= colSplit -> region2 (multiple of 128)
};

// ---------------------------------------------------------------------------
// NT MFMA GEMM: C[m,n] = sum_k A[m,k]*Bt[n,k]. 128x128 tile, BK=64,
// 256 threads = 4 waves 2x2, each wave 64x64 (4x4 MFMA subtiles).
// bf16 in (K-major both sides), fp32 accum. Column-split epilogue: cols >=
// colSplit go to C2 (optionally RoPE'd or transposed), B rows from B0r2.
// LDS rotation: slot s of row r holds chunk (s - r) & 7 (measured 0 confl).
// ---------------------------------------------------------------------------
template <int LDA0, int LDB0, int LDC, int LDC2, int FLAGS>
__global__ __launch_bounds__(256)
void gemm_mfma(GArgs g)
{
    __shared__ u16 As[128 * 64];   // 16 KB
    __shared__ u16 Bs[128 * 64];   // 16 KB

    const int t    = threadIdx.x;
    const int lane = t & 63;
    const int w    = t >> 6;
    const int wm   = w >> 1, wn = w & 1;
    const int m0   = blockIdx.y * 128;
    const int n0   = blockIdx.x * 128;
    const bool r2  = (n0 >= g.colSplit);

    const int srow = t >> 3;    // 0..31 base row for staging
    const int sp   = t & 7;     // LDS slot within row
    u16* dA = As + t * 8;
    u16* dB = Bs + t * 8;

    const int lr = lane & 15;
    const int jj = lane >> 4;

    f32x4 acc[4][4];
#pragma unroll
    for (int i = 0; i < 4; ++i)
#pragma unroll
        for (int j = 0; j < 4; ++j)
            acc[i][j] = (f32x4){0.f, 0.f, 0.f, 0.f};

    {
        const u16* A = g.A0;
        const u16* B = r2 ? g.B0r2 - (long)g.colSplit * LDB0 : g.B0;
        const u16* gA[4];
        const u16* gB[4];
#pragma unroll
        for (int r = 0; r < 4; ++r) {
            int row = r * 32 + srow;
            int gc  = (sp - row) & 7;
            gA[r] = A + (long)(m0 + row) * LDA0 + gc * 8;
            gB[r] = B + (long)(n0 + row) * LDB0 + gc * 8;
        }
        for (int kt = 0; kt < g.K0; kt += 64) {
#pragma unroll
            for (int r = 0; r < 4; ++r) {
                gl_lds16(gA[r], dA + r * 2048);
                gl_lds16(gB[r], dB + r * 2048);
                gA[r] += 64; gB[r] += 64;
            }
            __syncthreads();
#pragma unroll
            for (int s = 0; s < 2; ++s) {
                bf16x8 af[4], bfr[4];
#pragma unroll
                for (int mi = 0; mi < 4; ++mi) {
                    int row  = wm * 64 + mi * 16 + lr;
                    int slot = (s * 4 + jj + row) & 7;
                    af[mi] = *(const bf16x8*)&As[row * 64 + slot * 8];
                }
#pragma unroll
                for (int ni = 0; ni < 4; ++ni) {
                    int row  = wn * 64 + ni * 16 + lr;
                    int slot = (s * 4 + jj + row) & 7;
                    bfr[ni] = *(const bf16x8*)&Bs[row * 64 + slot * 8];
                }
#pragma unroll
                for (int mi = 0; mi < 4; ++mi)
#pragma unroll
                    for (int ni = 0; ni < 4; ++ni)
                        acc[mi][ni] = __builtin_amdgcn_mfma_f32_16x16x32_bf16(
                            af[mi], bfr[ni], acc[mi][ni], 0, 0, 0);
            }
            __syncthreads();
        }
    }

    // epilogue. C/D layout: col = lane&15, row = (lane>>4)*4 + reg.
    const int eCol0 = n0 + wn * 64 + lr;
    const int eRow0 = m0 + wm * 64 + jj * 4;
    const bool oddc = lane & 1;

    if (g.bias) {
#pragma unroll
        for (int ni = 0; ni < 4; ++ni) {
            float bv = g.bias[eCol0 + ni * 16];
#pragma unroll
            for (int mi = 0; mi < 4; ++mi) {
                acc[mi][ni][0] += bv; acc[mi][ni][1] += bv;
                acc[mi][ni][2] += bv; acc[mi][ni][3] += bv;
            }
        }
    }

    if (!r2) {
#pragma unroll
        for (int mi = 0; mi < 4; ++mi)
#pragma unroll
            for (int ni = 0; ni < 4; ++ni) {
                int rowb = eRow0 + mi * 16;
                int colg = eCol0 + ni * 16;
                if (FLAGS & FLAG_F32OUT) {
                    float* cp = (float*)g.C;
#pragma unroll
                    for (int i = 0; i < 4; ++i)
                        cp[(long)(rowb + i) * LDC + colg] = acc[mi][ni][i];
                } else {
                    u16* cp = (u16*)g.C;
#pragma unroll
                    for (int i = 0; i < 4; ++i)
                        cp[(long)(rowb + i) * LDC + colg] = f2us(acc[mi][ni][i]);
                }
            }
    } else if (FLAGS & FLAG_ROPE2) {
        // chain-free table rope (r10); rows never wrap mod 512 in a block.
        const float base_s = (float)(eRow0 & 511);
#pragma unroll
        for (int ni = 0; ni < 4; ++ni) {
            int col2 = eCol0 + ni * 16 - g.colSplit;
            int rp   = (col2 & 511) & ~1;
            float f  = __expf(-9.2103403719761836f * (float)rp * (1.0f / 512.0f));
            float Cm[4], Sm[4], ci[4], si[4];
            rope_cs(f, base_s, Cm, Sm, ci, si);
            u16* cp = (u16*)g.C2;
#pragma unroll
            for (int mi = 0; mi < 4; ++mi) {
                f32x4 v = acc[mi][ni];
                int rowb = eRow0 + mi * 16;
#pragma unroll
                for (int i = 0; i < 4; ++i) {
                    float cr = Cm[mi] * ci[i] - Sm[mi] * si[i];
                    float sr = Sm[mi] * ci[i] + Cm[mi] * si[i];
                    float other = __shfl_xor(v[i], 1, 64);
                    float ov = oddc ? (v[i] * cr + other * sr)
                                    : (v[i] * cr - other * sr);
                    cp[(long)(rowb + i) * LDC2 + col2] = f2us(ov);
                }
            }
        }
    } else {
#pragma unroll
        for (int mi = 0; mi < 4; ++mi)
#pragma unroll
            for (int ni = 0; ni < 4; ++ni) {
                int rowb = eRow0 + mi * 16;
                int col2 = eCol0 + ni * 16 - g.colSplit;
                if (FLAGS & FLAG_TRANS2) {
                    u16* cp = (u16*)g.C2 + (long)col2 * LDC2 + rowb;
                    ushort4 o4;
                    o4.x = f2us(acc[mi][ni][0]); o4.y = f2us(acc[mi][ni][1]);
                    o4.z = f2us(acc[mi][ni][2]); o4.w = f2us(acc[mi][ni][3]);
                    *(ushort4*)cp = o4;
                } else {
                    u16* cp = (u16*)g.C2;
#pragma unroll
                    for (int i = 0; i < 4; ++i)
                        cp[(long)(rowb + i) * LDC2 + col2] = f2us(acc[mi][ni][i]);
                }
            }
    }
}

// ---------------------------------------------------------------------------
// Merged up-proj dispatch (r9, measured 113.9 us): q-GEMM (2560 blocks, rope
// epilogue) and kv-GEMM (1024 blocks, transpose epilogue) interleaved 5:2 in
// groups of 7 (3584 = 7*512, bijective). Co-resident VALU-heavy rope blocks
// overlap MFMA/store-heavy kv blocks (m114 pipe co-schedule).
// r10: chain-free rope + s_setprio around MFMA (heterogeneous co-residents
// = T5 role-diversity regime).
// ---------------------------------------------------------------------------
struct U2 { GArgs q; GArgs kv; };

__global__ __launch_bounds__(256)
void gemm_up2(U2 u)
{
    __shared__ u16 As[128 * 64];   // 16 KB
    __shared__ u16 Bs[128 * 64];   // 16 KB

    const int fl = blockIdx.x;                 // 0..3583
    const int gi = fl / 7, ri = fl - gi * 7;   // group / rank
    const bool isQ = ri < 5;
    const int idx  = isQ ? gi * 5 + ri : gi * 2 + (ri - 5);
    int m0, n0;
    if (isQ) { n0 = (idx % 80) * 128; m0 = (idx / 80) * 128; }
    else     { n0 = (idx & 31) * 128; m0 = (idx >> 5) * 128; }
    const GArgs g = isQ ? u.q : u.kv;
    const bool r2 = (n0 >= 2048);

    const int t    = threadIdx.x;
    const int lane = t & 63;
    const int w    = t >> 6;
    const int wm   = w >> 1, wn = w & 1;

    const int srow = t >> 3;
    const int sp   = t & 7;
    u16* dA = As + t * 8;
    u16* dB = Bs + t * 8;

    const int lr = lane & 15;
    const int jj = lane >> 4;

    f32x4 acc[4][4];
#pragma unroll
    for (int i = 0; i < 4; ++i)
#pragma unroll
        for (int j = 0; j < 4; ++j)
            acc[i][j] = (f32x4){0.f, 0.f, 0.f, 0.f};

    {
        const u16* A = g.A0;
        const u16* B = r2 ? g.B0r2 - 2048l * 512 : g.B0;
        const u16* gA[4];
        const u16* gB[4];
#pragma unroll
        for (int r = 0; r < 4; ++r) {
            int row = r * 32 + srow;
            int gc  = (sp - row) & 7;
            gA[r] = A + (long)(m0 + row) * 1536 + gc * 8;
            gB[r] = B + (long)(n0 + row) * 512 + gc * 8;
        }
#pragma unroll 1
        for (int kt = 0; kt < 512; kt += 64) {
#pragma unroll
            for (int r = 0; r < 4; ++r) {
                gl_lds16(gA[r], dA + r * 2048);
                gl_lds16(gB[r], dB + r * 2048);
                gA[r] += 64; gB[r] += 64;
            }
            __syncthreads();
            __builtin_amdgcn_s_setprio(1);
#pragma unroll
            for (int s = 0; s < 2; ++s) {
                bf16x8 af[4], bfr[4];
#pragma unroll
                for (int mi = 0; mi < 4; ++mi) {
                    int row  = wm * 64 + mi * 16 + lr;
                    int slot = (s * 4 + jj + row) & 7;
                    af[mi] = *(const bf16x8*)&As[row * 64 + slot * 8];
                }
#pragma unroll
                for (int ni = 0; ni < 4; ++ni) {
                    int row  = wn * 64 + ni * 16 + lr;
                    int slot = (s * 4 + jj + row) & 7;
                    bfr[ni] = *(const bf16x8*)&Bs[row * 64 + slot * 8];
                }
#pragma unroll
                for (int mi = 0; mi < 4; ++mi)
#pragma unroll
                    for (int ni = 0; ni < 4; ++ni)
                        acc[mi][ni] = __builtin_amdgcn_mfma_f32_16x16x32_bf16(
                            af[mi], bfr[ni], acc[mi][ni], 0, 0, 0);
            }
            __builtin_amdgcn_s_setprio(0);
            __syncthreads();
        }
    }

    const int eCol0 = n0 + wn * 64 + lr;
    const int eRow0 = m0 + wm * 64 + jj * 4;
    const bool oddc = lane & 1;

#pragma unroll
    for (int ni = 0; ni < 4; ++ni) {
        float bv = g.bias[eCol0 + ni * 16];
#pragma unroll
        for (int mi = 0; mi < 4; ++mi) {
            acc[mi][ni][0] += bv; acc[mi][ni][1] += bv;
            acc[mi][ni][2] += bv; acc[mi][ni][3] += bv;
        }
    }

    if (!r2) {
        // region1: plain bf16, LDC=2048 (q_c or k_c)
        u16* cp = (u16*)g.C;
#pragma unroll
        for (int mi = 0; mi < 4; ++mi)
#pragma unroll
            for (int ni = 0; ni < 4; ++ni) {
                int rowb = eRow0 + mi * 16;
                int colg = eCol0 + ni * 16;
#pragma unroll
                for (int i = 0; i < 4; ++i)
                    cp[(long)(rowb + i) * 2048 + colg] = f2us(acc[mi][ni][i]);
            }
    } else if (isQ) {
        // chain-free rope region2 -> q_r, LDC2=8192
        const float base_s = (float)(eRow0 & 511);
#pragma unroll
        for (int ni = 0; ni < 4; ++ni) {
            int col2 = eCol0 + ni * 16 - 2048;
            int rp   = (col2 & 511) & ~1;
            float f  = __expf(-9.2103403719761836f * (float)rp * (1.0f / 512.0f));
            float Cm[4], Sm[4], ci[4], si[4];
            rope_cs(f, base_s, Cm, Sm, ci, si);
            u16* cp = (u16*)g.C2;
#pragma unroll
            for (int mi = 0; mi < 4; ++mi) {
                f32x4 v = acc[mi][ni];
                int rowb = eRow0 + mi * 16;
#pragma unroll
                for (int i = 0; i < 4; ++i) {
                    float cr = Cm[mi] * ci[i] - Sm[mi] * si[i];
                    float sr = Sm[mi] * ci[i] + Cm[mi] * si[i];
                    float other = __shfl_xor(v[i], 1, 64);
                    float ov = oddc ? (v[i] * cr + other * sr)
                                    : (v[i] * cr - other * sr);
                    cp[(long)(rowb + i) * 8192 + col2] = f2us(ov);
                }
            }
        }
    } else {
        // transpose region2 -> v_t, LDC2=4096
#pragma unroll
        for (int mi = 0; mi < 4; ++mi)
#pragma unroll
            for (int ni = 0; ni < 4; ++ni) {
                int rowb = eRow0 + mi * 16;
                int col2 = eCol0 + ni * 16 - 2048;
                u16* cp = (u16*)g.C2 + (long)col2 * 4096 + rowb;
                ushort4 o4;
                o4.x = f2us(acc[mi][ni][0]); o4.y = f2us(acc[mi][ni][1]);
                o4.z = f2us(acc[mi][ni][2]); o4.w = f2us(acc[mi][ni][3]);
                *(ushort4*)cp = o4;
            }
    }
}

// ---------------------------------------------------------------------------
// Fused attention (round-5 verbatim: best measured 82.5 us, 524K confl).
// per block = (b, h, 128 q-rows). Loops 4 key-tiles of 128:
//   S = qc.kc^T (K=128) + qr.kr^T (K=512)   [BK=64 staged, MFMA]
//   P = exp(S*scale) -> Ps (stride 136); l_sum partials (LDS atomics)
//   O += P.V  (V staged into Bs, 2 halves)
// XCD swizzle: 4 q-tile sharers of one z on the same XCD; bb = xcd
// (r5-measured FETCH 246->183 MB).
// ---------------------------------------------------------------------------
__global__ __launch_bounds__(256, 2)
void attn_fused(const u16* __restrict__ qc, const u16* __restrict__ kc,
                const u16* __restrict__ qr, const u16* __restrict__ kr,
                const u16* __restrict__ vt, u16* __restrict__ o)
{
    __shared__ u16 As[128 * 64];       // 16 KB  (BK=64)
    __shared__ u16 Bs[128 * 64];       // 16 KB
    __shared__ u16 Ps[128 * 136];      // 34 KB (pad 128->136 for banks)
    __shared__ float l_sum[128];

    const int t    = threadIdx.x;
    const int lane = t & 63;
    const int w    = t >> 6;
    const int wm   = w >> 1, wn = w & 1;

    const int flat = blockIdx.x + (blockIdx.y << 2);   // hw dispatch order
    const int xcd  = flat & 7;
    const int j    = flat >> 3;                        // 0..63
    const int m0   = (j >> 4) * 128;
    const int z    = xcd * 16 + (j & 15);              // 0..127
    const int bb   = z >> 4, h = z & 15;

    if (t < 128) l_sum[t] = 0.f;

    const int srow = t >> 3;
    const int sp   = t & 7;
    u16* dA = As + t * 8;
    u16* dB = Bs + t * 8;
    int rrow[4], rgc[4];
#pragma unroll
    for (int r = 0; r < 4; ++r) {
        rrow[r] = r * 32 + srow;
        rgc[r]  = (sp - rrow[r]) & 7;
    }

    const int lr = lane & 15;
    const int jj = lane >> 4;

    const u16* gqc[4];
    const u16* gqr[4];
#pragma unroll
    for (int r = 0; r < 4; ++r) {
        gqc[r] = qc + (long)(bb * 512 + m0 + rrow[r]) * 2048 + h * 128 + rgc[r] * 8;
        gqr[r] = qr + (long)(bb * 512 + m0 + rrow[r]) * 8192 + h * 512 + rgc[r] * 8;
    }

    f32x4 acc_o[4][4];
#pragma unroll
    for (int i = 0; i < 4; ++i)
#pragma unroll
        for (int j2 = 0; j2 < 4; ++j2) acc_o[i][j2] = (f32x4){0.f, 0.f, 0.f, 0.f};

    const float scale = 1.0f / 33.941125496954285f;   // 1/(sqrt(128)+sqrt(512))

    for (int nt = 0; nt < 4; ++nt) {
        const int n0k = nt * 128;

        f32x4 acc_s[4][4];
#pragma unroll
        for (int i = 0; i < 4; ++i)
#pragma unroll
            for (int j2 = 0; j2 < 4; ++j2) acc_s[i][j2] = (f32x4){0.f, 0.f, 0.f, 0.f};

        const u16* pa[4];
        const u16* pb[4];
#pragma unroll
        for (int r = 0; r < 4; ++r) {
            pa[r] = gqc[r];
            pb[r] = kc + (long)(bb * 512 + n0k + rrow[r]) * 2048 + h * 128 + rgc[r] * 8;
        }
        for (int seg = 0; seg < 2; ++seg) {
            int iters = seg == 0 ? 2 : 8;        // K=128, then K=512
            for (int kt = 0; kt < iters; ++kt) {
#pragma unroll
                for (int r = 0; r < 4; ++r) {
                    gl_lds16(pa[r], dA + r * 2048);
                    gl_lds16(pb[r], dB + r * 2048);
                    pa[r] += 64; pb[r] += 64;
                }
                __syncthreads();
#pragma unroll
                for (int s = 0; s < 2; ++s) {
                    bf16x8 af[4], bfr[4];
#pragma unroll
                    for (int mi = 0; mi < 4; ++mi) {
                        int row  = wm * 64 + mi * 16 + lr;
                        int slot = (s * 4 + jj + row) & 7;
                        af[mi] = *(const bf16x8*)&As[row * 64 + slot * 8];
                    }
#pragma unroll
                    for (int ni = 0; ni < 4; ++ni) {
                        int row  = wn * 64 + ni * 16 + lr;
                        int slot = (s * 4 + jj + row) & 7;
                        bfr[ni] = *(const bf16x8*)&Bs[row * 64 + slot * 8];
                    }
#pragma unroll
                    for (int mi = 0; mi < 4; ++mi)
#pragma unroll
                        for (int ni = 0; ni < 4; ++ni)
                            acc_s[mi][ni] = __builtin_amdgcn_mfma_f32_16x16x32_bf16(
                                af[mi], bfr[ni], acc_s[mi][ni], 0, 0, 0);
                }
                __syncthreads();
            }
            if (seg == 0) {
#pragma unroll
                for (int r = 0; r < 4; ++r) {
                    pa[r] = gqr[r];
                    pb[r] = kr + (long)(bb * 512 + n0k + rrow[r]) * 1536 + rgc[r] * 8;
                }
            }
        }

        // ---- P = exp(S*scale) -> Ps; l partial sums -> l_sum ----
#pragma unroll
        for (int mi = 0; mi < 4; ++mi) {
            float rowpart[4] = {0.f, 0.f, 0.f, 0.f};
#pragma unroll
            for (int ni = 0; ni < 4; ++ni) {
                f32x4 v = acc_s[mi][ni];
                int colP = wn * 64 + ni * 16 + lr;
#pragma unroll
                for (int i = 0; i < 4; ++i) {
                    float e = __expf(v[i] * scale);
                    rowpart[i] += e;
                    int rowP = wm * 64 + mi * 16 + jj * 4 + i;
                    Ps[rowP * 136 + colP] = f2us(e);
                }
            }
#pragma unroll
            for (int i = 0; i < 4; ++i) {
                float s4 = rowpart[i];
                s4 += __shfl_xor(s4, 1, 64);
                s4 += __shfl_xor(s4, 2, 64);
                s4 += __shfl_xor(s4, 4, 64);
                s4 += __shfl_xor(s4, 8, 64);
                if ((lane & 15) == 0)
                    atomicAdd(&l_sum[wm * 64 + mi * 16 + jj * 4 + i], s4);
            }
        }

        // ---- O += P.V  (V staged into Bs, 2 iters of 64 keys) ----
        const u16* pv[4];
#pragma unroll
        for (int r = 0; r < 4; ++r)
            pv[r] = vt + (long)(h * 128 + rrow[r]) * 4096 + bb * 512 + n0k + rgc[r] * 8;
        for (int kt = 0; kt < 2; ++kt) {
#pragma unroll
            for (int r = 0; r < 4; ++r) {
                gl_lds16(pv[r], dB + r * 2048);
                pv[r] += 64;
            }
            __syncthreads();
#pragma unroll
            for (int s = 0; s < 2; ++s) {
                bf16x8 af[4], bfr[4];
#pragma unroll
                for (int mi = 0; mi < 4; ++mi) {
                    int row = wm * 64 + mi * 16 + lr;
                    af[mi] = *(const bf16x8*)&Ps[row * 136 + kt * 64 + s * 32 + jj * 8];
                }
#pragma unroll
                for (int ni = 0; ni < 4; ++ni) {
                    int row  = wn * 64 + ni * 16 + lr;
                    int slot = (s * 4 + jj + row) & 7;
                    bfr[ni] = *(const bf16x8*)&Bs[row * 64 + slot * 8];
                }
#pragma unroll
                for (int mi = 0; mi < 4; ++mi)
#pragma unroll
                    for (int ni = 0; ni < 4; ++ni)
                        acc_o[mi][ni] = __builtin_amdgcn_mfma_f32_16x16x32_bf16(
                            af[mi], bfr[ni], acc_o[mi][ni], 0, 0, 0);
            }
            __syncthreads();
        }
    }

    // ---- epilogue: O / l, write o[bs][h*128 + vcol] ----
#pragma unroll
    for (int mi = 0; mi < 4; ++mi) {
#pragma unroll
        for (int i = 0; i < 4; ++i) {
            int row = wm * 64 + mi * 16 + jj * 4 + i;
            float linv = 1.0f / l_sum[row];
            long grow = (long)(bb * 512 + m0 + row) * 2048 + h * 128;
#pragma unroll
            for (int ni = 0; ni < 4; ++ni) {
                int colc = wn * 64 + ni * 16 + lr;
                o[grow + colc] = f2us(acc_o[mi][ni][i] * linv);
            }
        }
    }
}

// ---------------------------------------------------------------------------
// prep_all (r10): ALL prep work in ONE dispatch (was 3):
//   blocks [0,8192):        X fp32 -> bf16 (float4 vectorized)
//   blocks [8192,22528):    weight transpose-converts (32x32 LDS tiles)
//   blocks [22528,22590):   bias concats
// ---------------------------------------------------------------------------
struct Prep {
    const float* X; u16* Xb;
    const float *Wdq, *Wdkv, *Wkr, *Wuq, *Wuk, *Wuv, *Wqr, *Wfc;
    u16 *Wc1, *Wc2, *Wqr_t, *Wfc_t;
    const float *bdq, *bdkv, *bkr, *buq, *bqr, *buk, *buv;
    float *biasD, *biasQ, *biasK;
};

__global__ __launch_bounds__(256)
void prep_all(Prep a)
{
    __shared__ float tile[32][33];
    const int bid = blockIdx.x;

    if (bid < 8192) {                   // X convert
        int i = bid * 256 + threadIdx.x;
        float4 v = ((const float4*)a.X)[i];
        ushort4 o;
        o.x = f2us(v.x); o.y = f2us(v.y); o.z = f2us(v.z); o.w = f2us(v.w);
        ((ushort4*)a.Xb)[i] = o;
        return;
    }
    if (bid >= 22528) {                 // bias gather
        int i = (bid - 22528) * 256 + threadIdx.x;   // 0 .. 15871
        if (i < 1536) {
            float v = i < 512 ? a.bdq[i]
                              : (i < 1024 ? a.bdkv[i - 512] : a.bkr[i - 1024]);
            a.biasD[i] = v;
        } else if (i < 11776) {
            int j = i - 1536;
            a.biasQ[j] = j < 2048 ? a.buq[j] : a.bqr[j - 2048];
        } else {
            int j = i - 11776;
            a.biasK[j] = j < 2048 ? a.buk[j] : a.buv[j - 2048];
        }
        return;
    }

    // weight transpose-convert
    const int wb = bid - 8192;          // 0..14335
    const float* in; u16* out; int K, N, nx, ny;
    if (wb < 3072) {                    // Wc1: [Wdq|Wdkv|Wkr], K=2048 N=512
        int z = wb >> 10, rem = wb & 1023;
        in = z == 0 ? a.Wdq : (z == 1 ? a.Wdkv : a.Wkr);
        out = a.Wc1 + z * 1048576;
        K = 2048; N = 512; nx = rem & 15; ny = rem >> 4;
    } else if (wb < 6144) {             // Wc2: [Wuq|Wuk|Wuv], K=512 N=2048
        int l = wb - 3072, z = l >> 10, rem = l & 1023;
        in = z == 0 ? a.Wuq : (z == 1 ? a.Wuk : a.Wuv);
        out = a.Wc2 + z * 1048576;
        K = 512; N = 2048; nx = rem & 63; ny = rem >> 6;
    } else if (wb < 10240) {            // Wqr: K=512 N=8192
        int l = wb - 6144;
        in = a.Wqr; out = a.Wqr_t;
        K = 512; N = 8192; nx = l & 255; ny = l >> 8;
    } else {                            // Wfc: K=2048 N=2048
        int l = wb - 10240;
        in = a.Wfc; out = a.Wfc_t;
        K = 2048; N = 2048; nx = l & 63; ny = l >> 6;
    }
    const int n0 = nx * 32, k0 = ny * 32;
    const int c = threadIdx.x & 31, r0 = threadIdx.x >> 5;
#pragma unroll
    for (int j = 0; j < 4; ++j) {
        int r = r0 + j * 8;
        tile[r][c] = in[(long)(k0 + r) * N + n0 + c];
    }
    __syncthreads();
#pragma unroll
    for (int j = 0; j < 4; ++j) {
        int r = r0 + j * 8;
        out[(long)(n0 + r) * K + k0 + c] = f2us(tile[c][r]);
    }
}

// ---------------------------------------------------------------------------
extern "C" void kernel_launch(void* const* d_in, const int* in_sizes, int n_in,
                              void* d_out, int out_size, void* d_ws, size_t ws_size,
                              hipStream_t stream)
{
    (void)in_sizes; (void)n_in; (void)out_size; (void)ws_size;

    const float* X    = (const float*)d_in[0];
    const float* Wdq  = (const float*)d_in[1];  const float* bdq  = (const float*)d_in[2];
    const float* Wdkv = (const float*)d_in[3];  const float* bdkv = (const float*)d_in[4];
    const float* Wuq  = (const float*)d_in[5];  const float* buq  = (const float*)d_in[6];
    const float* Wuk  = (const float*)d_in[7];  const float* buk  = (const float*)d_in[8];
    const float* Wuv  = (const float*)d_in[9];  const float* buv  = (const float*)d_in[10];
    const float* Wqr  = (const float*)d_in[11]; const float* bqr  = (const float*)d_in[12];
    const float* Wkr  = (const float*)d_in[13]; const float* bkr  = (const float*)d_in[14];
    const float* Wfc  = (const float*)d_in[15]; const float* bfc  = (const float*)d_in[16];
    float* out = (float*)d_out;

    // workspace (u16 elems), ~184 MB + small fp32 bias tail. No attn buffer.
    u16* ws = (u16*)d_ws;
    u16* Xb     = ws;                 // [4096][2048]               8M
    u16* Wc1    = Xb   + 8388608;     // [Wdq_t|Wdkv_t|Wkr_t] = [1536][2048]  3M
    u16* Wc2    = Wc1  + 3145728;     // [Wuq_t|Wuk_t|Wuv_t]  = [6144][512]   3M
    u16* Wqr_t  = Wc2  + 3145728;     // [8192][512]                4M
    u16* Wfc_t  = Wqr_t + 4194304;    // [2048][2048]               4M
    u16* ckk    = Wfc_t + 4194304;    // [4096][1536] = c_q|c_kv|k_r  6M
    u16* q_c    = ckk  + 6291456;     // [4096][2048]               8M
    u16* k_c    = q_c  + 8388608;     // [4096][2048]               8M
    u16* v_t    = k_c  + 8388608;     // [2048][4096] (V^T)         8M
    u16* q_r    = v_t  + 8388608;     // [4096][8192]               32M
    u16* o      = q_r  + 33554432;    // [4096][2048]               8M
    float* biasD = (float*)(o + 8388608);   // 1536
    float* biasQ = biasD + 1536;            // 10240
    float* biasK = biasQ + 10240;           // 4096

    dim3 blk(256, 1, 1);

    // ---- prep: ONE dispatch (r10; was 3) ----
    {
        Prep a{X, Xb,
               Wdq, Wdkv, Wkr, Wuq, Wuk, Wuv, Wqr, Wfc,
               Wc1, Wc2, Wqr_t, Wfc_t,
               bdq, bdkv, bkr, buq, bqr, buk, buv,
               biasD, biasQ, biasK};
        prep_all<<<22590, blk, 0, stream>>>(a);
    }

    const int NOSPLIT = 1 << 30;

    {   // down-proj: ckk[4096][1536] = X @ [Wdq|Wdkv|Wkr] + bias, rope cols>=1024
        GArgs a{};
        a.A0 = Xb; a.B0 = Wc1; a.B0r2 = Wc1 + 2l * 1048576; a.K0 = 2048;
        a.bias = biasD; a.C = ckk; a.C2 = ckk + 1024;
        a.colSplit = 1024;
        gemm_mfma<2048, 2048, 1536, 1536, FLAG_ROPE2>
            <<<dim3(12, 32, 1), blk, 0, stream>>>(a);
    }
    {   // merged up-proj: [q_c|q_r(rope)] and [k_c|v^T] in one dispatch
        U2 u{};
        u.q.A0 = ckk; u.q.B0 = Wc2; u.q.B0r2 = Wqr_t; u.q.K0 = 512;
        u.q.bias = biasQ; u.q.C = q_c; u.q.C2 = q_r; u.q.colSplit = 2048;
        u.kv.A0 = ckk + 512; u.kv.B0 = Wc2 + 1048576;
        u.kv.B0r2 = Wc2 + 2l * 1048576; u.kv.K0 = 512;
        u.kv.bias = biasK; u.kv.C = k_c; u.kv.C2 = v_t; u.kv.colSplit = 2048;
        gemm_up2<<<3584, blk, 0, stream>>>(u);
    }

    // ---- fused attention: scores + softmax(C=0) + PV, no attn buffer ----
    attn_fused<<<dim3(4, 128, 1), blk, 0, stream>>>(
        q_c, k_c, q_r, ckk + 1024, v_t, o);

    // ---- final projection (fp32 out) ----
    {
        GArgs a{};
        a.A0 = o; a.B0 = Wfc_t; a.B0r2 = Wfc_t; a.K0 = 2048;
        a.bias = bfc; a.C = out; a.C2 = out;
        a.colSplit = NOSPLIT;
        gemm_mfma<2048, 2048, 2048, 1, FLAG_F32OUT>
            <<<dim3(16, 32, 1), blk, 0, stream>>>(a);
    }
}